// Round 15
// baseline (297.132 us; speedup 1.0000x reference)
//
#include <hip/hip_runtime.h>

#define HH 512
#define LL 2048
#define NN 64
#define TT 64           // chunk length (Ab^64 = squaring chain it==5)
#define CC 32           // chunks, CC*TT == LL
#define NLDA 68         // padded fp32 leading dim (Neumann matrix)
#define SP 72           // padded bf16 leading dim (MFMA operand mats)

typedef __attribute__((ext_vector_type(8))) short bf16x8_t;   // 8 bf16 = 4 VGPR
typedef __attribute__((ext_vector_type(4))) float floatx4;

__device__ __forceinline__ float2 cmul(float2 a, float2 b) {
    return make_float2(a.x * b.x - a.y * b.y, a.x * b.y + a.y * b.x);
}
__device__ __forceinline__ float2 crecip(float2 a) {
    float id = 1.0f / (a.x * a.x + a.y * a.y);
    return make_float2(a.x * id, -a.y * id);
}
template <int CTRL>
__device__ __forceinline__ float dpp_mov(float x) {
    return __int_as_float(__builtin_amdgcn_update_dpp(
        0, __float_as_int(x), CTRL, 0xf, 0xf, true));
}
__device__ __forceinline__ float wave_sum_bcast(float x) {
    x += dpp_mov<0x111>(x);
    x += dpp_mov<0x112>(x);
    x += dpp_mov<0x114>(x);
    x += dpp_mov<0x118>(x);
    x += dpp_mov<0x142>(x);
    x += dpp_mov<0x143>(x);
    return __int_as_float(__builtin_amdgcn_readlane(__float_as_int(x), 63));
}
__device__ __forceinline__ float rlane(float x, int i) {
    return __int_as_float(__builtin_amdgcn_readlane(__float_as_int(x), i));
}
__device__ __forceinline__ unsigned short f2bf(float f) {  // RNE
    unsigned int u = __float_as_uint(f);
    u += 0x7FFFu + ((u >> 16) & 1u);
    return (unsigned short)(u >> 16);
}
__device__ __forceinline__ float bf2f(unsigned short s) {
    return __uint_as_float(((unsigned int)s) << 16);
}

// Closed-form DPLR discretization for (h, n): da, DP, t, Bb. Call with tid<64.
__device__ __forceinline__ void closed_form(
    int h, int n,
    const float* __restrict__ Lre, const float* __restrict__ Lim,
    const float* __restrict__ Pre, const float* __restrict__ Pim,
    const float* __restrict__ Bre, const float* __restrict__ Bim,
    const float* __restrict__ logstep,
    float2& da, float2& DPv, float2& tv, float2& bb) {
    float step = expf(logstep[h]);
    float as = 2.0f / step;
    float lr = fminf(Lre[h * NN + n], -1e-4f);
    float li = Lim[h * NN + n];
    float2 a = make_float2(as + lr, li);
    float2 Dn = crecip(make_float2(as - lr, -li));
    float2 P = make_float2(Pre[h * NN + n], Pim[h * NN + n]);
    float2 Bv = make_float2(Bre[h * NN + n], Bim[h * NN + n]);
    float2 cP = make_float2(P.x, -P.y);
    float p2 = P.x * P.x + P.y * P.y;
    float2 rt = cmul(cmul(cP, Dn), Bv);
    float2 e = make_float2(wave_sum_bcast(Dn.x * p2), wave_sum_bcast(Dn.y * p2));
    float2 rv = make_float2(wave_sum_bcast(rt.x), wave_sum_bcast(rt.y));
    float2 cc = crecip(make_float2(1.0f + e.x, e.y));
    da = cmul(Dn, a);
    DPv = cmul(Dn, P);
    float2 tmp = cmul(cc, make_float2(da.x - e.x, da.y - e.y));
    tv = cmul(cP, make_float2(1.0f + tmp.x, tmp.y));
    float2 crv = cmul(cc, rv);
    float2 cd = cmul(crv, DPv);
    float2 db = cmul(Dn, Bv);
    bb = make_float2(2.0f * (db.x - cd.x), 2.0f * (db.y - cd.y));
}

// Pack a lane's 4x4-per-ntile fp32 complex tile into hi/lo bf16, row-major
// mats (Rh/Rl/Ih/Il) + transposed mats (TRh/TRl/TIh/TIl, T[c][k]=A[k][c]).
__device__ __forceinline__ void pack_tiles(
    unsigned short* mRh, unsigned short* mRl,
    unsigned short* mIh, unsigned short* mIl,
    unsigned short* mTRh, unsigned short* mTRl,
    unsigned short* mTIh, unsigned short* mTIl,
    int w, int lm, int q, const float Cr[4][4], const float Ci[4][4]) {
    #pragma unroll
    for (int nt = 0; nt < 4; ++nt) {
        const int c = nt * 16 + lm;
        unsigned short hr[4], lr_[4], hi_[4], li_[4];
        #pragma unroll
        for (int reg = 0; reg < 4; ++reg) {
            const float xr = Cr[nt][reg], xi = Ci[nt][reg];
            hr[reg] = f2bf(xr); lr_[reg] = f2bf(xr - bf2f(hr[reg]));
            hi_[reg] = f2bf(xi); li_[reg] = f2bf(xi - bf2f(hi_[reg]));
            const int r = 16 * w + 4 * q + reg;
            mRh[r * SP + c] = hr[reg]; mRl[r * SP + c] = lr_[reg];
            mIh[r * SP + c] = hi_[reg]; mIl[r * SP + c] = li_[reg];
        }
        const int tb = c * SP + 16 * w + 4 * q;
        *(ushort4*)&mTRh[tb] = make_ushort4(hr[0], hr[1], hr[2], hr[3]);
        *(ushort4*)&mTRl[tb] = make_ushort4(lr_[0], lr_[1], lr_[2], lr_[3]);
        *(ushort4*)&mTIh[tb] = make_ushort4(hi_[0], hi_[1], hi_[2], hi_[3]);
        *(ushort4*)&mTIl[tb] = make_ushort4(li_[0], li_[1], li_[2], li_[3]);
    }
}

// Fused kernel A, grid = 1024 x 256 thr, dyn LDS 78848 B.
// Blocks 0..511   (precompute head h): MFMA squaring chain (bf16 hi/lo),
//   M=Ab^64 at it==5 -> wM, Ab^2048 -> Neumann solve -> wCb.
// Blocks 512..1023 (stage1 head h): closed-form + G recurrence + p_c GEMM.
extern "C" __global__ void __launch_bounds__(256, 2)
k_fusedA(const float* __restrict__ Lre, const float* __restrict__ Lim,
         const float* __restrict__ Pre, const float* __restrict__ Pim,
         const float* __restrict__ Bre, const float* __restrict__ Bim,
         const float* __restrict__ Cmat, const float* __restrict__ logstep,
         const float* __restrict__ u,
         float2* __restrict__ wM, float2* __restrict__ wCb,
         float2* __restrict__ wP) {
    extern __shared__ __align__(16) char smem[];
    const int tid = threadIdx.x;

    if (blockIdx.x < HH) {
        // ------------------------- precompute -------------------------
        const int h = blockIdx.x;
        unsigned short* mRh  = (unsigned short*)smem;          // 9216 B each
        unsigned short* mRl  = mRh + 64 * SP;
        unsigned short* mIh  = mRl + 64 * SP;
        unsigned short* mIl  = mIh + 64 * SP;
        unsigned short* mTRh = mIl + 64 * SP;
        unsigned short* mTRl = mTRh + 64 * SP;
        unsigned short* mTIh = mTRl + 64 * SP;
        unsigned short* mTIl = mTIh + 64 * SP;                 // ends 73728
        float* Nr = (float*)smem;                               // overlay
        float* Ni = Nr + 64 * NLDA;                             // 34816 B
        float2* sda  = (float2*)(smem + 73728);
        float2* sDP  = sda + NN;
        float2* st   = sDP + NN;
        float2* sBb  = st + NN;
        float2* srhs = sBb + NN;
        float2* sx   = srhs + NN;
        float2* pp   = sx + NN;                                 // 256 float2

        const int w = tid >> 6;
        const int lane = tid & 63;
        const int lm = lane & 15, q = lane >> 4;

        if (tid < NN) {
            float2 da, DPv, tv, bb;
            closed_form(h, tid, Lre, Lim, Pre, Pim, Bre, Bim, logstep,
                        da, DPv, tv, bb);
            sda[tid] = da; sDP[tid] = DPv; st[tid] = tv; sBb[tid] = bb;
            srhs[tid] = make_float2(Cmat[h * NN * 2 + tid * 2],
                                    -Cmat[h * NN * 2 + tid * 2 + 1]);
        }
        __syncthreads();

        // Build Ab = diag(da) - DP (x) t in tile layout, pack.
        {
            float Cr[4][4], Ci[4][4];
            #pragma unroll
            for (int nt = 0; nt < 4; ++nt) {
                const int c = nt * 16 + lm;
                const float2 tc = st[c];
                #pragma unroll
                for (int reg = 0; reg < 4; ++reg) {
                    const int r = 16 * w + 4 * q + reg;
                    const float2 dp = sDP[r];
                    float vr = -(dp.x * tc.x - dp.y * tc.y);
                    float vi = -(dp.x * tc.y + dp.y * tc.x);
                    if (r == c) { vr += sda[r].x; vi += sda[r].y; }
                    Cr[nt][reg] = vr; Ci[nt][reg] = vi;
                }
            }
            pack_tiles(mRh, mRl, mIh, mIl, mTRh, mTRl, mTIh, mTIl,
                       w, lm, q, Cr, Ci);
        }
        __syncthreads();

        // 11 squarings on MFMA.
        const int arow = (16 * w + lm) * SP + q * 8;
        for (int it = 0; it < 11; ++it) {
            floatx4 z4 = {0.f, 0.f, 0.f, 0.f};
            floatx4 aP[4] = {z4, z4, z4, z4};
            floatx4 aQ[4] = {z4, z4, z4, z4};
            floatx4 aC[4] = {z4, z4, z4, z4};
            for (int k2 = 0; k2 < 2; ++k2) {
                const int ao = arow + k2 * 32;
                const bf16x8_t ARh = *(const bf16x8_t*)&mRh[ao];
                const bf16x8_t ARl = *(const bf16x8_t*)&mRl[ao];
                const bf16x8_t AIh = *(const bf16x8_t*)&mIh[ao];
                const bf16x8_t AIl = *(const bf16x8_t*)&mIl[ao];
                bf16x8_t BRh[4], BRl[4], BIh[4], BIl[4];
                #pragma unroll
                for (int nt = 0; nt < 4; ++nt) {
                    const int bo = (nt * 16 + lm) * SP + k2 * 32 + q * 8;
                    BRh[nt] = *(const bf16x8_t*)&mTRh[bo];
                    BRl[nt] = *(const bf16x8_t*)&mTRl[bo];
                    BIh[nt] = *(const bf16x8_t*)&mTIh[bo];
                    BIl[nt] = *(const bf16x8_t*)&mTIl[bo];
                }
                #pragma unroll
                for (int nt = 0; nt < 4; ++nt) {
                    aP[nt] = __builtin_amdgcn_mfma_f32_16x16x32_bf16(ARh, BRh[nt], aP[nt], 0, 0, 0);
                    aP[nt] = __builtin_amdgcn_mfma_f32_16x16x32_bf16(ARh, BRl[nt], aP[nt], 0, 0, 0);
                    aP[nt] = __builtin_amdgcn_mfma_f32_16x16x32_bf16(ARl, BRh[nt], aP[nt], 0, 0, 0);
                    aQ[nt] = __builtin_amdgcn_mfma_f32_16x16x32_bf16(AIh, BIh[nt], aQ[nt], 0, 0, 0);
                    aQ[nt] = __builtin_amdgcn_mfma_f32_16x16x32_bf16(AIh, BIl[nt], aQ[nt], 0, 0, 0);
                    aQ[nt] = __builtin_amdgcn_mfma_f32_16x16x32_bf16(AIl, BIh[nt], aQ[nt], 0, 0, 0);
                    aC[nt] = __builtin_amdgcn_mfma_f32_16x16x32_bf16(ARh, BIh[nt], aC[nt], 0, 0, 0);
                    aC[nt] = __builtin_amdgcn_mfma_f32_16x16x32_bf16(ARh, BIl[nt], aC[nt], 0, 0, 0);
                    aC[nt] = __builtin_amdgcn_mfma_f32_16x16x32_bf16(ARl, BIh[nt], aC[nt], 0, 0, 0);
                    aC[nt] = __builtin_amdgcn_mfma_f32_16x16x32_bf16(AIh, BRh[nt], aC[nt], 0, 0, 0);
                    aC[nt] = __builtin_amdgcn_mfma_f32_16x16x32_bf16(AIh, BRl[nt], aC[nt], 0, 0, 0);
                    aC[nt] = __builtin_amdgcn_mfma_f32_16x16x32_bf16(AIl, BRh[nt], aC[nt], 0, 0, 0);
                }
            }
            __syncthreads();   // all frag reads complete before overwrite
            if (it < 10) {
                float Cr[4][4], Ci[4][4];
                #pragma unroll
                for (int nt = 0; nt < 4; ++nt)
                    #pragma unroll
                    for (int reg = 0; reg < 4; ++reg) {
                        Cr[nt][reg] = aP[nt][reg] - aQ[nt][reg];
                        Ci[nt][reg] = aC[nt][reg];
                    }
                pack_tiles(mRh, mRl, mIh, mIl, mTRh, mTRl, mTIh, mTIl,
                           w, lm, q, Cr, Ci);
                __syncthreads();
                if (it == 5) {
                    // emit M = Ab^64 transposed: wM[h][c*64+k] = M[k][c]
                    for (int idx = tid; idx < NN * NN; idx += 256) {
                        const int c = idx >> 6, k = idx & 63;
                        wM[h * NN * NN + idx] = make_float2(
                            bf2f(mTRh[c * SP + k]) + bf2f(mTRl[c * SP + k]),
                            bf2f(mTIh[c * SP + k]) + bf2f(mTIl[c * SP + k]));
                    }
                }
            } else {
                // final: N = Ab^2048 -> fp32 overlay
                #pragma unroll
                for (int nt = 0; nt < 4; ++nt) {
                    const int c = nt * 16 + lm;
                    #pragma unroll
                    for (int reg = 0; reg < 4; ++reg) {
                        const int r = 16 * w + 4 * q + reg;
                        Nr[r * NLDA + c] = aP[nt][reg] - aQ[nt][reg];
                        Ni[r * NLDA + c] = aC[nt][reg];
                    }
                }
                __syncthreads();
            }
        }

        // Neumann: Cb = sum_k (N^T)^k c,  ||N|| <= 0.36  (24 iters ~ 2e-11)
        if (tid < NN) sx[tid] = srhs[tid];
        __syncthreads();
        for (int itn = 0; itn < 24; ++itn) {
            const int i = tid & 63, qq = tid >> 6;
            float pr = 0.0f, pi = 0.0f;
            #pragma unroll 4
            for (int jj = 0; jj < 16; ++jj) {
                const int j = qq * 16 + jj;
                const float nr = Nr[j * NLDA + i], ni = Ni[j * NLDA + i];
                const float2 xj = sx[j];
                pr += nr * xj.x - ni * xj.y;
                pi += nr * xj.y + ni * xj.x;
            }
            pp[qq * 64 + i] = make_float2(pr, pi);
            __syncthreads();
            if (tid < NN) {
                const float2 a0 = pp[tid], a1 = pp[64 + tid];
                const float2 a2 = pp[128 + tid], a3 = pp[192 + tid];
                sx[tid] = make_float2(
                    srhs[tid].x + a0.x + a1.x + a2.x + a3.x,
                    srhs[tid].y + a0.y + a1.y + a2.y + a3.y);
            }
            __syncthreads();
        }
        if (tid < NN) wCb[h * NN + tid] = sx[tid];
    } else {
        // --------------------------- stage1 ---------------------------
        const int h = blockIdx.x - HH;
        float2* sG  = (float2*)smem;                 // [m*64+n], 32768 B
        float*  su  = (float*)(smem + 32768);        // 8192 B
        float2* sda = (float2*)(smem + 40960);
        float2* sDP = sda + NN;
        float2* st  = sDP + NN;
        float2* sBb = st + NN;

        const int wv = tid >> 6, lane = tid & 63;
        for (int idx = tid; idx < LL; idx += 256)
            su[idx] = u[idx * HH + h];
        if (tid < NN) {
            float2 da, DPv, tv, bb;
            closed_form(h, tid, Lre, Lim, Pre, Pim, Bre, Bim, logstep,
                        da, DPv, tv, bb);
            sda[tid] = da; sDP[tid] = DPv; st[tid] = tv; sBb[tid] = bb;
        }
        __syncthreads();

        if (tid < 64) {
            const float2 da = sda[lane], DP = sDP[lane], tt = st[lane];
            float Gr = sBb[lane].x, Gi = sBb[lane].y;
            for (int m = 0; m < TT; ++m) {
                sG[m * NN + lane] = make_float2(Gr, Gi);
                float c1 = tt.x * Gr - tt.y * Gi;
                float c2 = tt.x * Gi + tt.y * Gr;
                c1 += dpp_mov<0x111>(c1); c2 += dpp_mov<0x111>(c2);
                c1 += dpp_mov<0x112>(c1); c2 += dpp_mov<0x112>(c2);
                c1 += dpp_mov<0x114>(c1); c2 += dpp_mov<0x114>(c2);
                c1 += dpp_mov<0x118>(c1); c2 += dpp_mov<0x118>(c2);
                c1 += dpp_mov<0x142>(c1); c2 += dpp_mov<0x142>(c2);
                c1 += dpp_mov<0x143>(c1); c2 += dpp_mov<0x143>(c2);
                const float S1 = rlane(c1, 63);
                const float S2 = rlane(c2, 63);
                float nGr = da.x * Gr - da.y * Gi - (DP.x * S1 - DP.y * S2);
                float nGi = da.x * Gi + da.y * Gr - (DP.x * S2 + DP.y * S1);
                Gr = nGr; Gi = nGi;
            }
        }
        __syncthreads();

        float accr[8] = {}, acci[8] = {};
        for (int j = 0; j < TT; ++j) {
            const float2 g = sG[(TT - 1 - j) * NN + lane];
            #pragma unroll
            for (int qc = 0; qc < 8; ++qc) {
                const float uv = su[((wv * 8 + qc) << 6) + j];
                accr[qc] += g.x * uv; acci[qc] += g.y * uv;
            }
        }
        #pragma unroll
        for (int qc = 0; qc < 8; ++qc)
            wP[(h * CC + wv * 8 + qc) * NN + lane] = make_float2(accr[qc], acci[qc]);
    }
}

// Fused kernel B, grid = 512 (one block per head), 256 thr, dyn LDS 74496 B.
// Phase 1: load M + u into LDS. Phase 2 (concurrent): wave 0 Krylov
// (V_m = Cb^T Ab^{m+1} -> bf16 LDS, K_m), wave 1 sequential combine
// (x_start(c) = M x + p, fp32; wP software-pipelined into registers).
// Phase 3: all waves stage2 (float4 su conv) -> out (direct).
extern "C" __global__ void __launch_bounds__(256, 2)
k_fusedB(const float* __restrict__ Lre, const float* __restrict__ Lim,
         const float* __restrict__ Pre, const float* __restrict__ Pim,
         const float* __restrict__ Bre, const float* __restrict__ Bim,
         const float* __restrict__ logstep,
         const float* __restrict__ u, const float* __restrict__ Dvec,
         const float* __restrict__ x0_re, const float* __restrict__ x0_im,
         const float2* __restrict__ wM, const float2* __restrict__ wCb,
         const float2* __restrict__ wP, float* __restrict__ out) {
    extern __shared__ __align__(16) char smem[];
    float2* sM          = (float2*)smem;                    // 32768 B  [j*64+i]=M[i][j]
    unsigned short* sVr = (unsigned short*)(smem + 32768);  // 8448 B   [n*66+m]
    unsigned short* sVi = (unsigned short*)(smem + 41216);  // 8448 B
    float2* sXs         = (float2*)(smem + 49664);          // 16384 B  [c*64+n]
    float*  su          = (float*)(smem + 66048);           // 8192 B
    float*  sK          = (float*)(smem + 74240);           // 256 B

    const int h = blockIdx.x;
    const int tid = threadIdx.x;
    const int wv = tid >> 6, lane = tid & 63;

    for (int idx = tid; idx < NN * NN; idx += 256)
        sM[idx] = wM[h * NN * NN + idx];
    for (int idx = tid; idx < LL; idx += 256)
        su[idx] = u[idx * HH + h];
    __syncthreads();

    if (wv == 0) {
        // Krylov: G_m = Ab^m Bb, v = Cb^T Ab^{m+1}; V -> bf16, K -> LDS.
        float2 da, DP, tt, Bb;
        closed_form(h, lane, Lre, Lim, Pre, Pim, Bre, Bim, logstep,
                    da, DP, tt, Bb);
        const float2 Cb = wCb[h * NN + lane];
        float Gr = Bb.x, Gi = Bb.y;
        float vr = Cb.x, vi = Cb.y;
        for (int m = 0; m < TT; ++m) {
            float ch[5];
            ch[0] = Cb.x * Gr - Cb.y * Gi;
            ch[1] = tt.x * Gr - tt.y * Gi;
            ch[2] = tt.x * Gi + tt.y * Gr;
            ch[3] = vr * DP.x - vi * DP.y;
            ch[4] = vr * DP.y + vi * DP.x;
            #pragma unroll
            for (int c = 0; c < 5; ++c) ch[c] += dpp_mov<0x111>(ch[c]);
            #pragma unroll
            for (int c = 0; c < 5; ++c) ch[c] += dpp_mov<0x112>(ch[c]);
            #pragma unroll
            for (int c = 0; c < 5; ++c) ch[c] += dpp_mov<0x114>(ch[c]);
            #pragma unroll
            for (int c = 0; c < 5; ++c) ch[c] += dpp_mov<0x118>(ch[c]);
            #pragma unroll
            for (int c = 0; c < 5; ++c) ch[c] += dpp_mov<0x142>(ch[c]);
            #pragma unroll
            for (int c = 0; c < 5; ++c) ch[c] += dpp_mov<0x143>(ch[c]);
            const float S0 = rlane(ch[0], 63);
            const float S1 = rlane(ch[1], 63);
            const float S2 = rlane(ch[2], 63);
            const float S3 = rlane(ch[3], 63);
            const float S4 = rlane(ch[4], 63);
            if (lane == 0) sK[m] = S0;
            float nGr = da.x * Gr - da.y * Gi - (DP.x * S1 - DP.y * S2);
            float nGi = da.x * Gi + da.y * Gr - (DP.x * S2 + DP.y * S1);
            Gr = nGr; Gi = nGi;
            float nvr = da.x * vr - da.y * vi - (S3 * tt.x - S4 * tt.y);
            float nvi = da.x * vi + da.y * vr - (S3 * tt.y + S4 * tt.x);
            vr = nvr; vi = nvi;
            sVr[lane * 66 + m] = f2bf(vr);
            sVi[lane * 66 + m] = f2bf(vi);
        }
    } else if (wv == 1) {
        // Combine: x_start(c) = M x_start(c-1) + p_{c-1} (fp32, sequential).
        // wP loads software-pipelined one iteration ahead (hides latency).
        float xr = x0_re[lane * HH + h], xi = x0_im[lane * HH + h];
        sXs[lane] = make_float2(xr, xi);
        float2 pe_next = wP[(h * CC + 0) * NN + lane];
        for (int c = 1; c < CC; ++c) {
            const float2 pe = pe_next;
            if (c < CC - 1) pe_next = wP[(h * CC + c) * NN + lane];
            float nr = 0.0f, ni = 0.0f;
            #pragma unroll 8
            for (int j = 0; j < NN; ++j) {
                const float xjr = rlane(xr, j);
                const float xji = rlane(xi, j);
                const float2 m = sM[j * NN + lane];
                nr += m.x * xjr - m.y * xji;
                ni += m.x * xji + m.y * xjr;
            }
            xr = nr + pe.x; xi = ni + pe.y;
            sXs[c * NN + lane] = make_float2(xr, xi);
        }
    }
    __syncthreads();

    // stage2: y[c][t] = Re(V_t . x_start(c)) + sum_{s<=t} K[t-s] u[c][s] + D u[c][t]
    const float Dh = Dvec[h];
    const int t = lane;
    float acc[8] = {};
    for (int s4 = 0; s4 < 16; ++s4) {
        const int s0 = s4 << 2;
        float kv[4];
        #pragma unroll
        for (int j = 0; j < 4; ++j) {
            const int d = t - (s0 + j);
            kv[j] = (d >= 0) ? sK[d < 0 ? 0 : d] : 0.0f;
        }
        #pragma unroll
        for (int qc = 0; qc < 8; ++qc) {
            const float4 uv4 = *(const float4*)&su[((wv * 8 + qc) << 6) + s0];
            acc[qc] += kv[0] * uv4.x + kv[1] * uv4.y + kv[2] * uv4.z + kv[3] * uv4.w;
        }
    }
    for (int n = 0; n < NN; ++n) {
        const float vvr = bf2f(sVr[n * 66 + t]);
        const float vvi = bf2f(sVi[n * 66 + t]);
        #pragma unroll
        for (int qc = 0; qc < 8; ++qc) {
            const float2 xs = sXs[(wv * 8 + qc) * NN + n];
            acc[qc] += vvr * xs.x - vvi * xs.y;
        }
    }
    #pragma unroll
    for (int qc = 0; qc < 8; ++qc) {
        const int c = wv * 8 + qc;
        out[(c * TT + t) * HH + h] = acc[qc] + Dh * su[c * TT + t];
    }
}

extern "C" void kernel_launch(void* const* d_in, const int* in_sizes, int n_in,
                              void* d_out, int out_size, void* d_ws, size_t ws_size,
                              hipStream_t stream) {
    const float* u    = (const float*)d_in[0];
    const float* x0re = (const float*)d_in[1];
    const float* x0im = (const float*)d_in[2];
    const float* Lre  = (const float*)d_in[3];
    const float* Lim  = (const float*)d_in[4];
    const float* Pre  = (const float*)d_in[5];
    const float* Pim  = (const float*)d_in[6];
    const float* Bre  = (const float*)d_in[7];
    const float* Bim  = (const float*)d_in[8];
    const float* C    = (const float*)d_in[9];
    const float* Dv   = (const float*)d_in[10];
    const float* lst  = (const float*)d_in[11];

    float2* wM  = (float2*)d_ws;                 // 16.8 MB
    float2* wP  = wM + HH * NN * NN;             // 8.4 MB
    float2* wCb = wP + HH * CC * NN;             // 256 KB
    float* out = (float*)d_out;

    hipLaunchKernelGGL(k_fusedA, dim3(2 * HH), dim3(256), 78848, stream,
                       Lre, Lim, Pre, Pim, Bre, Bim, C, lst, u,
                       wM, wCb, wP);
    hipLaunchKernelGGL(k_fusedB, dim3(HH), dim3(256), 74496, stream,
                       Lre, Lim, Pre, Pim, Bre, Bim, lst, u, Dv,
                       x0re, x0im, wM, wCb, wP, out);
}

// Round 16
// 226.894 us; speedup vs baseline: 1.3096x; 1.3096x over previous
//
#include <hip/hip_runtime.h>

#define HH 512
#define LL 2048
#define NN 64
#define TT 64           // chunk length (Ab^64 = squaring chain it==5)
#define CC 32           // chunks, CC*TT == LL
#define NLDA 68         // padded fp32 leading dim (Neumann matrix)
#define SP 72           // padded bf16 leading dim (MFMA operand mats)

typedef __attribute__((ext_vector_type(8))) short bf16x8_t;   // 8 bf16 = 4 VGPR
typedef __attribute__((ext_vector_type(4))) float floatx4;

__device__ __forceinline__ float2 cmul(float2 a, float2 b) {
    return make_float2(a.x * b.x - a.y * b.y, a.x * b.y + a.y * b.x);
}
__device__ __forceinline__ float2 crecip(float2 a) {
    float id = 1.0f / (a.x * a.x + a.y * a.y);
    return make_float2(a.x * id, -a.y * id);
}
template <int CTRL>
__device__ __forceinline__ float dpp_mov(float x) {
    return __int_as_float(__builtin_amdgcn_update_dpp(
        0, __float_as_int(x), CTRL, 0xf, 0xf, true));
}
__device__ __forceinline__ float wave_sum_bcast(float x) {
    x += dpp_mov<0x111>(x);
    x += dpp_mov<0x112>(x);
    x += dpp_mov<0x114>(x);
    x += dpp_mov<0x118>(x);
    x += dpp_mov<0x142>(x);
    x += dpp_mov<0x143>(x);
    return __int_as_float(__builtin_amdgcn_readlane(__float_as_int(x), 63));
}
__device__ __forceinline__ float rlane(float x, int i) {
    return __int_as_float(__builtin_amdgcn_readlane(__float_as_int(x), i));
}
__device__ __forceinline__ unsigned short f2bf(float f) {  // RNE
    unsigned int u = __float_as_uint(f);
    u += 0x7FFFu + ((u >> 16) & 1u);
    return (unsigned short)(u >> 16);
}
__device__ __forceinline__ float bf2f(unsigned short s) {
    return __uint_as_float(((unsigned int)s) << 16);
}

// Closed-form DPLR discretization for (h, n): da, DP, t, Bb. Call with tid<64.
__device__ __forceinline__ void closed_form(
    int h, int n,
    const float* __restrict__ Lre, const float* __restrict__ Lim,
    const float* __restrict__ Pre, const float* __restrict__ Pim,
    const float* __restrict__ Bre, const float* __restrict__ Bim,
    const float* __restrict__ logstep,
    float2& da, float2& DPv, float2& tv, float2& bb) {
    float step = expf(logstep[h]);
    float as = 2.0f / step;
    float lr = fminf(Lre[h * NN + n], -1e-4f);
    float li = Lim[h * NN + n];
    float2 a = make_float2(as + lr, li);
    float2 Dn = crecip(make_float2(as - lr, -li));
    float2 P = make_float2(Pre[h * NN + n], Pim[h * NN + n]);
    float2 Bv = make_float2(Bre[h * NN + n], Bim[h * NN + n]);
    float2 cP = make_float2(P.x, -P.y);
    float p2 = P.x * P.x + P.y * P.y;
    float2 rt = cmul(cmul(cP, Dn), Bv);
    float2 e = make_float2(wave_sum_bcast(Dn.x * p2), wave_sum_bcast(Dn.y * p2));
    float2 rv = make_float2(wave_sum_bcast(rt.x), wave_sum_bcast(rt.y));
    float2 cc = crecip(make_float2(1.0f + e.x, e.y));
    da = cmul(Dn, a);
    DPv = cmul(Dn, P);
    float2 tmp = cmul(cc, make_float2(da.x - e.x, da.y - e.y));
    tv = cmul(cP, make_float2(1.0f + tmp.x, tmp.y));
    float2 crv = cmul(cc, rv);
    float2 cd = cmul(crv, DPv);
    float2 db = cmul(Dn, Bv);
    bb = make_float2(2.0f * (db.x - cd.x), 2.0f * (db.y - cd.y));
}

// Pack a lane's 4x4-per-ntile fp32 complex tile into hi/lo bf16, row-major
// mats (Rh/Rl/Ih/Il) + transposed mats (TRh/TRl/TIh/TIl, T[c][k]=A[k][c]).
__device__ __forceinline__ void pack_tiles(
    unsigned short* mRh, unsigned short* mRl,
    unsigned short* mIh, unsigned short* mIl,
    unsigned short* mTRh, unsigned short* mTRl,
    unsigned short* mTIh, unsigned short* mTIl,
    int w, int lm, int q, const float Cr[4][4], const float Ci[4][4]) {
    #pragma unroll
    for (int nt = 0; nt < 4; ++nt) {
        const int c = nt * 16 + lm;
        unsigned short hr[4], lr_[4], hi_[4], li_[4];
        #pragma unroll
        for (int reg = 0; reg < 4; ++reg) {
            const float xr = Cr[nt][reg], xi = Ci[nt][reg];
            hr[reg] = f2bf(xr); lr_[reg] = f2bf(xr - bf2f(hr[reg]));
            hi_[reg] = f2bf(xi); li_[reg] = f2bf(xi - bf2f(hi_[reg]));
            const int r = 16 * w + 4 * q + reg;
            mRh[r * SP + c] = hr[reg]; mRl[r * SP + c] = lr_[reg];
            mIh[r * SP + c] = hi_[reg]; mIl[r * SP + c] = li_[reg];
        }
        const int tb = c * SP + 16 * w + 4 * q;
        *(ushort4*)&mTRh[tb] = make_ushort4(hr[0], hr[1], hr[2], hr[3]);
        *(ushort4*)&mTRl[tb] = make_ushort4(lr_[0], lr_[1], lr_[2], lr_[3]);
        *(ushort4*)&mTIh[tb] = make_ushort4(hi_[0], hi_[1], hi_[2], hi_[3]);
        *(ushort4*)&mTIl[tb] = make_ushort4(li_[0], li_[1], li_[2], li_[3]);
    }
}

// Fused kernel A, grid = 1024 x 256 thr, dyn LDS 78848 B.
// Blocks 0..511   (precompute head h): MFMA squaring chain (bf16 hi/lo),
//   M=Ab^64 at it==5 -> wM, Ab^2048 -> Neumann solve -> wCb.
// Blocks 512..1023 (stage1 head h): closed-form + G recurrence + p_c GEMM.
extern "C" __global__ void __launch_bounds__(256, 2)
k_fusedA(const float* __restrict__ Lre, const float* __restrict__ Lim,
         const float* __restrict__ Pre, const float* __restrict__ Pim,
         const float* __restrict__ Bre, const float* __restrict__ Bim,
         const float* __restrict__ Cmat, const float* __restrict__ logstep,
         const float* __restrict__ u,
         float2* __restrict__ wM, float2* __restrict__ wCb,
         float2* __restrict__ wP) {
    extern __shared__ __align__(16) char smem[];
    const int tid = threadIdx.x;

    if (blockIdx.x < HH) {
        // ------------------------- precompute -------------------------
        const int h = blockIdx.x;
        unsigned short* mRh  = (unsigned short*)smem;          // 9216 B each
        unsigned short* mRl  = mRh + 64 * SP;
        unsigned short* mIh  = mRl + 64 * SP;
        unsigned short* mIl  = mIh + 64 * SP;
        unsigned short* mTRh = mIl + 64 * SP;
        unsigned short* mTRl = mTRh + 64 * SP;
        unsigned short* mTIh = mTRl + 64 * SP;
        unsigned short* mTIl = mTIh + 64 * SP;                 // ends 73728
        float* Nr = (float*)smem;                               // overlay
        float* Ni = Nr + 64 * NLDA;                             // 34816 B
        float2* sda  = (float2*)(smem + 73728);
        float2* sDP  = sda + NN;
        float2* st   = sDP + NN;
        float2* sBb  = st + NN;
        float2* srhs = sBb + NN;
        float2* sx   = srhs + NN;
        float2* pp   = sx + NN;                                 // 256 float2

        const int w = tid >> 6;
        const int lane = tid & 63;
        const int lm = lane & 15, q = lane >> 4;

        if (tid < NN) {
            float2 da, DPv, tv, bb;
            closed_form(h, tid, Lre, Lim, Pre, Pim, Bre, Bim, logstep,
                        da, DPv, tv, bb);
            sda[tid] = da; sDP[tid] = DPv; st[tid] = tv; sBb[tid] = bb;
            srhs[tid] = make_float2(Cmat[h * NN * 2 + tid * 2],
                                    -Cmat[h * NN * 2 + tid * 2 + 1]);
        }
        __syncthreads();

        // Build Ab = diag(da) - DP (x) t in tile layout, pack.
        {
            float Cr[4][4], Ci[4][4];
            #pragma unroll
            for (int nt = 0; nt < 4; ++nt) {
                const int c = nt * 16 + lm;
                const float2 tc = st[c];
                #pragma unroll
                for (int reg = 0; reg < 4; ++reg) {
                    const int r = 16 * w + 4 * q + reg;
                    const float2 dp = sDP[r];
                    float vr = -(dp.x * tc.x - dp.y * tc.y);
                    float vi = -(dp.x * tc.y + dp.y * tc.x);
                    if (r == c) { vr += sda[r].x; vi += sda[r].y; }
                    Cr[nt][reg] = vr; Ci[nt][reg] = vi;
                }
            }
            pack_tiles(mRh, mRl, mIh, mIl, mTRh, mTRl, mTIh, mTIl,
                       w, lm, q, Cr, Ci);
        }
        __syncthreads();

        // 11 squarings on MFMA.
        const int arow = (16 * w + lm) * SP + q * 8;
        for (int it = 0; it < 11; ++it) {
            floatx4 z4 = {0.f, 0.f, 0.f, 0.f};
            floatx4 aP[4] = {z4, z4, z4, z4};
            floatx4 aQ[4] = {z4, z4, z4, z4};
            floatx4 aC[4] = {z4, z4, z4, z4};
            for (int k2 = 0; k2 < 2; ++k2) {
                const int ao = arow + k2 * 32;
                const bf16x8_t ARh = *(const bf16x8_t*)&mRh[ao];
                const bf16x8_t ARl = *(const bf16x8_t*)&mRl[ao];
                const bf16x8_t AIh = *(const bf16x8_t*)&mIh[ao];
                const bf16x8_t AIl = *(const bf16x8_t*)&mIl[ao];
                bf16x8_t BRh[4], BRl[4], BIh[4], BIl[4];
                #pragma unroll
                for (int nt = 0; nt < 4; ++nt) {
                    const int bo = (nt * 16 + lm) * SP + k2 * 32 + q * 8;
                    BRh[nt] = *(const bf16x8_t*)&mTRh[bo];
                    BRl[nt] = *(const bf16x8_t*)&mTRl[bo];
                    BIh[nt] = *(const bf16x8_t*)&mTIh[bo];
                    BIl[nt] = *(const bf16x8_t*)&mTIl[bo];
                }
                #pragma unroll
                for (int nt = 0; nt < 4; ++nt) {
                    aP[nt] = __builtin_amdgcn_mfma_f32_16x16x32_bf16(ARh, BRh[nt], aP[nt], 0, 0, 0);
                    aP[nt] = __builtin_amdgcn_mfma_f32_16x16x32_bf16(ARh, BRl[nt], aP[nt], 0, 0, 0);
                    aP[nt] = __builtin_amdgcn_mfma_f32_16x16x32_bf16(ARl, BRh[nt], aP[nt], 0, 0, 0);
                    aQ[nt] = __builtin_amdgcn_mfma_f32_16x16x32_bf16(AIh, BIh[nt], aQ[nt], 0, 0, 0);
                    aQ[nt] = __builtin_amdgcn_mfma_f32_16x16x32_bf16(AIh, BIl[nt], aQ[nt], 0, 0, 0);
                    aQ[nt] = __builtin_amdgcn_mfma_f32_16x16x32_bf16(AIl, BIh[nt], aQ[nt], 0, 0, 0);
                    aC[nt] = __builtin_amdgcn_mfma_f32_16x16x32_bf16(ARh, BIh[nt], aC[nt], 0, 0, 0);
                    aC[nt] = __builtin_amdgcn_mfma_f32_16x16x32_bf16(ARh, BIl[nt], aC[nt], 0, 0, 0);
                    aC[nt] = __builtin_amdgcn_mfma_f32_16x16x32_bf16(ARl, BIh[nt], aC[nt], 0, 0, 0);
                    aC[nt] = __builtin_amdgcn_mfma_f32_16x16x32_bf16(AIh, BRh[nt], aC[nt], 0, 0, 0);
                    aC[nt] = __builtin_amdgcn_mfma_f32_16x16x32_bf16(AIh, BRl[nt], aC[nt], 0, 0, 0);
                    aC[nt] = __builtin_amdgcn_mfma_f32_16x16x32_bf16(AIl, BRh[nt], aC[nt], 0, 0, 0);
                }
            }
            __syncthreads();   // all frag reads complete before overwrite
            if (it < 10) {
                float Cr[4][4], Ci[4][4];
                #pragma unroll
                for (int nt = 0; nt < 4; ++nt)
                    #pragma unroll
                    for (int reg = 0; reg < 4; ++reg) {
                        Cr[nt][reg] = aP[nt][reg] - aQ[nt][reg];
                        Ci[nt][reg] = aC[nt][reg];
                    }
                pack_tiles(mRh, mRl, mIh, mIl, mTRh, mTRl, mTIh, mTIl,
                           w, lm, q, Cr, Ci);
                __syncthreads();
                if (it == 5) {
                    // emit M = Ab^64 transposed: wM[h][c*64+k] = M[k][c]
                    for (int idx = tid; idx < NN * NN; idx += 256) {
                        const int c = idx >> 6, k = idx & 63;
                        wM[h * NN * NN + idx] = make_float2(
                            bf2f(mTRh[c * SP + k]) + bf2f(mTRl[c * SP + k]),
                            bf2f(mTIh[c * SP + k]) + bf2f(mTIl[c * SP + k]));
                    }
                }
            } else {
                // final: N = Ab^2048 -> fp32 overlay
                #pragma unroll
                for (int nt = 0; nt < 4; ++nt) {
                    const int c = nt * 16 + lm;
                    #pragma unroll
                    for (int reg = 0; reg < 4; ++reg) {
                        const int r = 16 * w + 4 * q + reg;
                        Nr[r * NLDA + c] = aP[nt][reg] - aQ[nt][reg];
                        Ni[r * NLDA + c] = aC[nt][reg];
                    }
                }
                __syncthreads();
            }
        }

        // Neumann: Cb = sum_k (N^T)^k c,  ||N|| <= 0.36  (24 iters ~ 2e-11)
        if (tid < NN) sx[tid] = srhs[tid];
        __syncthreads();
        for (int itn = 0; itn < 24; ++itn) {
            const int i = tid & 63, qq = tid >> 6;
            float pr = 0.0f, pi = 0.0f;
            #pragma unroll 4
            for (int jj = 0; jj < 16; ++jj) {
                const int j = qq * 16 + jj;
                const float nr = Nr[j * NLDA + i], ni = Ni[j * NLDA + i];
                const float2 xj = sx[j];
                pr += nr * xj.x - ni * xj.y;
                pi += nr * xj.y + ni * xj.x;
            }
            pp[qq * 64 + i] = make_float2(pr, pi);
            __syncthreads();
            if (tid < NN) {
                const float2 a0 = pp[tid], a1 = pp[64 + tid];
                const float2 a2 = pp[128 + tid], a3 = pp[192 + tid];
                sx[tid] = make_float2(
                    srhs[tid].x + a0.x + a1.x + a2.x + a3.x,
                    srhs[tid].y + a0.y + a1.y + a2.y + a3.y);
            }
            __syncthreads();
        }
        if (tid < NN) wCb[h * NN + tid] = sx[tid];
    } else {
        // --------------------------- stage1 ---------------------------
        const int h = blockIdx.x - HH;
        float2* sG  = (float2*)smem;                 // [m*64+n], 32768 B
        float*  su  = (float*)(smem + 32768);        // 8192 B
        float2* sda = (float2*)(smem + 40960);
        float2* sDP = sda + NN;
        float2* st  = sDP + NN;
        float2* sBb = st + NN;

        const int wv = tid >> 6, lane = tid & 63;
        for (int idx = tid; idx < LL; idx += 256)
            su[idx] = u[idx * HH + h];
        if (tid < NN) {
            float2 da, DPv, tv, bb;
            closed_form(h, tid, Lre, Lim, Pre, Pim, Bre, Bim, logstep,
                        da, DPv, tv, bb);
            sda[tid] = da; sDP[tid] = DPv; st[tid] = tv; sBb[tid] = bb;
        }
        __syncthreads();

        if (tid < 64) {
            const float2 da = sda[lane], DP = sDP[lane], tt = st[lane];
            float Gr = sBb[lane].x, Gi = sBb[lane].y;
            for (int m = 0; m < TT; ++m) {
                sG[m * NN + lane] = make_float2(Gr, Gi);
                float c1 = tt.x * Gr - tt.y * Gi;
                float c2 = tt.x * Gi + tt.y * Gr;
                c1 += dpp_mov<0x111>(c1); c2 += dpp_mov<0x111>(c2);
                c1 += dpp_mov<0x112>(c1); c2 += dpp_mov<0x112>(c2);
                c1 += dpp_mov<0x114>(c1); c2 += dpp_mov<0x114>(c2);
                c1 += dpp_mov<0x118>(c1); c2 += dpp_mov<0x118>(c2);
                c1 += dpp_mov<0x142>(c1); c2 += dpp_mov<0x142>(c2);
                c1 += dpp_mov<0x143>(c1); c2 += dpp_mov<0x143>(c2);
                const float S1 = rlane(c1, 63);
                const float S2 = rlane(c2, 63);
                float nGr = da.x * Gr - da.y * Gi - (DP.x * S1 - DP.y * S2);
                float nGi = da.x * Gi + da.y * Gr - (DP.x * S2 + DP.y * S1);
                Gr = nGr; Gi = nGi;
            }
        }
        __syncthreads();

        float accr[8] = {}, acci[8] = {};
        for (int j = 0; j < TT; ++j) {
            const float2 g = sG[(TT - 1 - j) * NN + lane];
            #pragma unroll
            for (int qc = 0; qc < 8; ++qc) {
                const float uv = su[((wv * 8 + qc) << 6) + j];
                accr[qc] += g.x * uv; acci[qc] += g.y * uv;
            }
        }
        #pragma unroll
        for (int qc = 0; qc < 8; ++qc)
            wP[(h * CC + wv * 8 + qc) * NN + lane] = make_float2(accr[qc], acci[qc]);
    }
}

// Fused kernel B, grid = 512 (one block per head), 256 thr, dyn LDS 74496 B.
// Phase 1: load M + u into LDS. Phase 2 (concurrent): wave 0 Krylov
// (V_m = Cb^T Ab^{m+1} -> bf16 LDS, K_m), wave 1 sequential combine
// (x_start(c) = M x + p, fp32; wP software-pipelined into registers).
// Phase 3: all waves stage2 -> out (direct).
extern "C" __global__ void __launch_bounds__(256, 2)
k_fusedB(const float* __restrict__ Lre, const float* __restrict__ Lim,
         const float* __restrict__ Pre, const float* __restrict__ Pim,
         const float* __restrict__ Bre, const float* __restrict__ Bim,
         const float* __restrict__ logstep,
         const float* __restrict__ u, const float* __restrict__ Dvec,
         const float* __restrict__ x0_re, const float* __restrict__ x0_im,
         const float2* __restrict__ wM, const float2* __restrict__ wCb,
         const float2* __restrict__ wP, float* __restrict__ out) {
    extern __shared__ __align__(16) char smem[];
    float2* sM          = (float2*)smem;                    // 32768 B  [j*64+i]=M[i][j]
    unsigned short* sVr = (unsigned short*)(smem + 32768);  // 8448 B   [n*66+m]
    unsigned short* sVi = (unsigned short*)(smem + 41216);  // 8448 B
    float2* sXs         = (float2*)(smem + 49664);          // 16384 B  [c*64+n]
    float*  su          = (float*)(smem + 66048);           // 8192 B
    float*  sK          = (float*)(smem + 74240);           // 256 B

    const int h = blockIdx.x;
    const int tid = threadIdx.x;
    const int wv = tid >> 6, lane = tid & 63;

    for (int idx = tid; idx < NN * NN; idx += 256)
        sM[idx] = wM[h * NN * NN + idx];
    for (int idx = tid; idx < LL; idx += 256)
        su[idx] = u[idx * HH + h];
    __syncthreads();

    if (wv == 0) {
        // Krylov: G_m = Ab^m Bb, v = Cb^T Ab^{m+1}; V -> bf16, K -> LDS.
        float2 da, DP, tt, Bb;
        closed_form(h, lane, Lre, Lim, Pre, Pim, Bre, Bim, logstep,
                    da, DP, tt, Bb);
        const float2 Cb = wCb[h * NN + lane];
        float Gr = Bb.x, Gi = Bb.y;
        float vr = Cb.x, vi = Cb.y;
        for (int m = 0; m < TT; ++m) {
            float ch[5];
            ch[0] = Cb.x * Gr - Cb.y * Gi;
            ch[1] = tt.x * Gr - tt.y * Gi;
            ch[2] = tt.x * Gi + tt.y * Gr;
            ch[3] = vr * DP.x - vi * DP.y;
            ch[4] = vr * DP.y + vi * DP.x;
            #pragma unroll
            for (int c = 0; c < 5; ++c) ch[c] += dpp_mov<0x111>(ch[c]);
            #pragma unroll
            for (int c = 0; c < 5; ++c) ch[c] += dpp_mov<0x112>(ch[c]);
            #pragma unroll
            for (int c = 0; c < 5; ++c) ch[c] += dpp_mov<0x114>(ch[c]);
            #pragma unroll
            for (int c = 0; c < 5; ++c) ch[c] += dpp_mov<0x118>(ch[c]);
            #pragma unroll
            for (int c = 0; c < 5; ++c) ch[c] += dpp_mov<0x142>(ch[c]);
            #pragma unroll
            for (int c = 0; c < 5; ++c) ch[c] += dpp_mov<0x143>(ch[c]);
            const float S0 = rlane(ch[0], 63);
            const float S1 = rlane(ch[1], 63);
            const float S2 = rlane(ch[2], 63);
            const float S3 = rlane(ch[3], 63);
            const float S4 = rlane(ch[4], 63);
            if (lane == 0) sK[m] = S0;
            float nGr = da.x * Gr - da.y * Gi - (DP.x * S1 - DP.y * S2);
            float nGi = da.x * Gi + da.y * Gr - (DP.x * S2 + DP.y * S1);
            Gr = nGr; Gi = nGi;
            float nvr = da.x * vr - da.y * vi - (S3 * tt.x - S4 * tt.y);
            float nvi = da.x * vi + da.y * vr - (S3 * tt.y + S4 * tt.x);
            vr = nvr; vi = nvi;
            sVr[lane * 66 + m] = f2bf(vr);
            sVi[lane * 66 + m] = f2bf(vi);
        }
    } else if (wv == 1) {
        // Combine: x_start(c) = M x_start(c-1) + p_{c-1} (fp32, sequential).
        // wP loads software-pipelined one iteration ahead (hides latency).
        float xr = x0_re[lane * HH + h], xi = x0_im[lane * HH + h];
        sXs[lane] = make_float2(xr, xi);
        float2 pe_next = wP[(h * CC + 0) * NN + lane];
        for (int c = 1; c < CC; ++c) {
            const float2 pe = pe_next;
            if (c < CC - 1) pe_next = wP[(h * CC + c) * NN + lane];
            float nr = 0.0f, ni = 0.0f;
            #pragma unroll 8
            for (int j = 0; j < NN; ++j) {
                const float xjr = rlane(xr, j);
                const float xji = rlane(xi, j);
                const float2 m = sM[j * NN + lane];
                nr += m.x * xjr - m.y * xji;
                ni += m.x * xji + m.y * xjr;
            }
            xr = nr + pe.x; xi = ni + pe.y;
            sXs[c * NN + lane] = make_float2(xr, xi);
        }
    }
    __syncthreads();

    // stage2: y[c][t] = Re(V_t . x_start(c)) + sum_{s<=t} K[t-s] u[c][s] + D u[c][t]
    const float Dh = Dvec[h];
    const int t = lane;
    float acc[8] = {};
    for (int s = 0; s < TT; ++s) {
        const int d = t - s;
        const float kv = (d >= 0) ? sK[d < 0 ? 0 : d] : 0.0f;
        #pragma unroll
        for (int qc = 0; qc < 8; ++qc)
            acc[qc] += kv * su[((wv * 8 + qc) << 6) + s];
    }
    for (int n = 0; n < NN; ++n) {
        const float vvr = bf2f(sVr[n * 66 + t]);
        const float vvi = bf2f(sVi[n * 66 + t]);
        #pragma unroll
        for (int qc = 0; qc < 8; ++qc) {
            const float2 xs = sXs[(wv * 8 + qc) * NN + n];
            acc[qc] += vvr * xs.x - vvi * xs.y;
        }
    }
    #pragma unroll
    for (int qc = 0; qc < 8; ++qc) {
        const int c = wv * 8 + qc;
        out[(c * TT + t) * HH + h] = acc[qc] + Dh * su[c * TT + t];
    }
}

extern "C" void kernel_launch(void* const* d_in, const int* in_sizes, int n_in,
                              void* d_out, int out_size, void* d_ws, size_t ws_size,
                              hipStream_t stream) {
    const float* u    = (const float*)d_in[0];
    const float* x0re = (const float*)d_in[1];
    const float* x0im = (const float*)d_in[2];
    const float* Lre  = (const float*)d_in[3];
    const float* Lim  = (const float*)d_in[4];
    const float* Pre  = (const float*)d_in[5];
    const float* Pim  = (const float*)d_in[6];
    const float* Bre  = (const float*)d_in[7];
    const float* Bim  = (const float*)d_in[8];
    const float* C    = (const float*)d_in[9];
    const float* Dv   = (const float*)d_in[10];
    const float* lst  = (const float*)d_in[11];

    float2* wM  = (float2*)d_ws;                 // 16.8 MB
    float2* wP  = wM + HH * NN * NN;             // 8.4 MB
    float2* wCb = wP + HH * CC * NN;             // 256 KB
    float* out = (float*)d_out;

    hipLaunchKernelGGL(k_fusedA, dim3(2 * HH), dim3(256), 78848, stream,
                       Lre, Lim, Pre, Pim, Bre, Bim, C, lst, u,
                       wM, wCb, wP);
    hipLaunchKernelGGL(k_fusedB, dim3(HH), dim3(256), 74496, stream,
                       Lre, Lim, Pre, Pim, Bre, Bim, lst, u, Dv,
                       x0re, x0im, wM, wCb, wP, out);
}